// Round 6
// baseline (10255.653 us; speedup 1.0000x reference)
//
#include <hip/hip_runtime.h>
#include <hip/hip_bf16.h>
#include <stdint.h>
#include <math.h>

// LSTM: S=200, B=128, NINP=400, NHID=1150, 3 layers.
// Padded dims: HP=1152 (H pad), G4=4*HP, KP0=448 (NINP pad). M = S*B = 25600.
// x_proj computed in chunks of CH=50 timesteps to cap workspace at ~199 MB.
#define HP 1152
#define G4 4608
#define MT 25600
#define KP0 448
#define CH 50

typedef __attribute__((ext_vector_type(8))) short short8;
typedef __attribute__((ext_vector_type(4))) float f32x4;

static __device__ __forceinline__ void mfma16(f32x4& d, short8 a, short8 b) {
  // D = A(16x32) * B(32x16) + D, bf16 inputs, fp32 accum. Inline asm avoids
  // builtin operand-type ambiguity; C/D layout: col=lane&15, row=(lane>>4)*4+r.
  asm volatile("v_mfma_f32_16x16x32_bf16 %0, %1, %2, %0" : "+v"(d) : "v"(a), "v"(b));
}

// ---------------- pack / init kernels ----------------

__global__ void k_embed(const int* __restrict__ tok, const float* __restrict__ emb,
                        __hip_bfloat16* __restrict__ x0) {
  const int n = MT * KP0;
  for (int i = blockIdx.x * blockDim.x + threadIdx.x; i < n; i += gridDim.x * blockDim.x) {
    int m = i / KP0, d = i - m * KP0;
    float v = (d < 400) ? emb[(size_t)tok[m] * 400 + d] : 0.0f;
    x0[i] = __float2bfloat16(v);
  }
}

__global__ void k_packw(const float* __restrict__ src, __hip_bfloat16* __restrict__ dst,
                        int Ksrc, int Kp) {
  const int n = G4 * Kp;
  for (int i = blockIdx.x * blockDim.x + threadIdx.x; i < n; i += gridDim.x * blockDim.x) {
    int r = i / Kp, k = i - r * Kp;
    int g = r / HP, j = r - g * HP;
    float v = (j < 1150 && k < Ksrc) ? src[(size_t)(g * 1150 + j) * Ksrc + k] : 0.0f;
    dst[i] = __float2bfloat16(v);
  }
}

__global__ void k_packb(const float* __restrict__ bi, const float* __restrict__ bh,
                        float* __restrict__ dst) {
  int i = blockIdx.x * blockDim.x + threadIdx.x;
  if (i < G4) {
    int g = i / HP, j = i - g * HP;
    dst[i] = (j < 1150) ? (bi[g * 1150 + j] + bh[g * 1150 + j]) : 0.0f;
  }
}

__global__ void k_inith(const float* __restrict__ src, __hip_bfloat16* __restrict__ dst) {
  int i = blockIdx.x * blockDim.x + threadIdx.x;
  if (i < 128 * HP) {
    int b = i / HP, k = i - b * HP;
    dst[i] = __float2bfloat16(k < 1150 ? src[b * 1150 + k] : 0.0f);
  }
}

__global__ void k_initc(const float* __restrict__ src, float* __restrict__ dst) {
  int i = blockIdx.x * blockDim.x + threadIdx.x;
  if (i < 128 * HP) {
    int b = i / HP, k = i - b * HP;
    dst[i] = (k < 1150) ? src[b * 1150 + k] : 0.0f;
  }
}

// ---------------- x_proj GEMM: C[rows,G4](bf16) = A[rows,Kp] * B[G4,Kp]^T + bias ----------------
// 128x128 tile, BK=64, 4 waves (each 64x64 = 4x4 MFMA tiles), reg-staged LDS,
// XOR swizzle (c8 ^= row&7) on both LDS write and read sides. Called per 50-step
// chunk (grid 1800 = 50 row-tiles x 36 col-tiles); A/C bases point at the chunk.

__global__ __launch_bounds__(256) void k_gemm(const __hip_bfloat16* __restrict__ A,
                                              const __hip_bfloat16* __restrict__ B,
                                              const float* __restrict__ bias,
                                              __hip_bfloat16* __restrict__ C, int Kp) {
  __shared__ __hip_bfloat16 As[128][64];
  __shared__ __hip_bfloat16 Bs[128][64];
  int bid = blockIdx.x;
  int cpx = gridDim.x >> 3;               // XCD swizzle (grid % 8 == 0)
  bid = (bid & 7) * cpx + (bid >> 3);
  const int bm = bid / 36, bn = bid - bm * 36;
  const int tid = threadIdx.x, w = tid >> 6, lane = tid & 63;
  const int lr = lane & 15, kg = lane >> 4;
  const int wm = (w >> 1) * 64, wn = (w & 1) * 64;
  f32x4 acc[4][4];
#pragma unroll
  for (int i = 0; i < 4; ++i)
#pragma unroll
    for (int j = 0; j < 4; ++j) {
      f32x4 z = {0.f, 0.f, 0.f, 0.f};
      acc[i][j] = z;
    }
  const char* Ab = (const char*)A + (size_t)bm * (size_t)(128 * Kp * 2);
  const char* Bb = (const char*)B + (size_t)bn * (size_t)(128 * Kp * 2);
  const size_t rs = (size_t)Kp * 2;
  const int nK = Kp >> 6;
  for (int kt = 0; kt < nK; ++kt) {
    const size_t kb = (size_t)kt << 7;
    short8 va[4], vb[4];
#pragma unroll
    for (int c = 0; c < 4; ++c) {
      int idx = c * 256 + tid;
      int row = idx >> 3, c8 = idx & 7;
      va[c] = *(const short8*)(Ab + (size_t)row * rs + kb + c8 * 16);
      vb[c] = *(const short8*)(Bb + (size_t)row * rs + kb + c8 * 16);
    }
    __syncthreads();  // previous compute done before LDS overwrite
#pragma unroll
    for (int c = 0; c < 4; ++c) {
      int idx = c * 256 + tid;
      int row = idx >> 3, c8 = idx & 7;
      int sc = (c8 ^ (row & 7)) << 3;
      *(short8*)&As[row][sc] = va[c];
      *(short8*)&Bs[row][sc] = vb[c];
    }
    __syncthreads();
#pragma unroll
    for (int h = 0; h < 2; ++h) {
      const int sw = ((h * 4 + kg) ^ (lr & 7)) << 3;
      short8 af[4], bf[4];
#pragma unroll
      for (int mt = 0; mt < 4; ++mt) af[mt] = *(const short8*)&As[wm + mt * 16 + lr][sw];
#pragma unroll
      for (int nt = 0; nt < 4; ++nt) bf[nt] = *(const short8*)&Bs[wn + nt * 16 + lr][sw];
#pragma unroll
      for (int mt = 0; mt < 4; ++mt)
#pragma unroll
        for (int nt = 0; nt < 4; ++nt) mfma16(acc[mt][nt], af[mt], bf[nt]);
    }
  }
  asm volatile("s_nop 7\n\ts_nop 7\n\ts_nop 7");  // MFMA->read-D hazard guard (asm bypasses recognizer)
  const int cr = (lane >> 4) << 2, cc = lane & 15;
#pragma unroll
  for (int nt = 0; nt < 4; ++nt) {
    const int gcol = bn * 128 + wn + nt * 16 + cc;
    const float bv = bias[gcol];
#pragma unroll
    for (int mt = 0; mt < 4; ++mt) {
      const int grow = bm * 128 + wm + mt * 16 + cr;
#pragma unroll
      for (int r = 0; r < 4; ++r)
        C[(size_t)(grow + r) * G4 + gcol] = __float2bfloat16(acc[mt][nt][r] + bv);
    }
  }
}

// ---------------- fused LSTM step ----------------
// gates = x_proj[t] + h_t @ Whh^T ; cell update fused in epilogue.
// Grid 144 = 4 row-groups x 36 gate-col-groups. Block: 32 rows x 32 cols x 4 gates,
// wave w computes gate w (2x2 MFMA tiles, K=1152). Gate exchange via LDS for cell.

__global__ __launch_bounds__(256) void k_step(const __hip_bfloat16* __restrict__ Hin,
                                              const __hip_bfloat16* __restrict__ Whh,
                                              const __hip_bfloat16* __restrict__ XP,
                                              float* __restrict__ Cst,
                                              __hip_bfloat16* __restrict__ Hout,
                                              float* __restrict__ Yout,
                                              float* __restrict__ HT,
                                              float* __restrict__ CT) {
  __shared__ __hip_bfloat16 As[32][64];
  __shared__ __hip_bfloat16 Bs[4][32][64];
  __shared__ float Xch[4][32][32];
  const int tid = threadIdx.x, w = tid >> 6, lane = tid & 63;
  const int bm = blockIdx.x / 36, bg = blockIdx.x - bm * 36;
  const int rb = bm << 5, gc0 = bg << 5;
  const int lr = lane & 15, kg = lane >> 4;
  f32x4 acc[2][2];
  {
    f32x4 z = {0.f, 0.f, 0.f, 0.f};
    acc[0][0] = z; acc[0][1] = z; acc[1][0] = z; acc[1][1] = z;
  }
  const char* Hb = (const char*)Hin + (size_t)rb * (HP * 2);
  const char* Wb = (const char*)Whh + (size_t)(w * HP + gc0) * (HP * 2);
  const int arow = tid >> 3, ac8 = tid & 7;
  for (int kt = 0; kt < 18; ++kt) {
    const size_t kb = (size_t)kt << 7;
    short8 va = *(const short8*)(Hb + (size_t)arow * (HP * 2) + kb + ac8 * 16);
    short8 vb[4];
#pragma unroll
    for (int c = 0; c < 4; ++c) {
      int idx = (c << 6) + lane;
      int row = idx >> 3, c8 = idx & 7;
      vb[c] = *(const short8*)(Wb + (size_t)row * (HP * 2) + kb + c8 * 16);
    }
    __syncthreads();
    *(short8*)&As[arow][(ac8 ^ (arow & 7)) << 3] = va;
#pragma unroll
    for (int c = 0; c < 4; ++c) {
      int idx = (c << 6) + lane;
      int row = idx >> 3, c8 = idx & 7;
      *(short8*)&Bs[w][row][(c8 ^ (row & 7)) << 3] = vb[c];
    }
    __syncthreads();
#pragma unroll
    for (int h = 0; h < 2; ++h) {
      const int sw = ((h * 4 + kg) ^ (lr & 7)) << 3;
      short8 a0 = *(const short8*)&As[lr][sw];
      short8 a1 = *(const short8*)&As[16 + lr][sw];
      short8 b0 = *(const short8*)&Bs[w][lr][sw];
      short8 b1 = *(const short8*)&Bs[w][16 + lr][sw];
      mfma16(acc[0][0], a0, b0);
      mfma16(acc[0][1], a0, b1);
      mfma16(acc[1][0], a1, b0);
      mfma16(acc[1][1], a1, b1);
    }
  }
  asm volatile("s_nop 7\n\ts_nop 7\n\ts_nop 7");  // MFMA->ds_write hazard guard
  const int cr = (lane >> 4) << 2, cc = lane & 15;
#pragma unroll
  for (int mt = 0; mt < 2; ++mt)
#pragma unroll
    for (int nt = 0; nt < 2; ++nt)
#pragma unroll
      for (int r = 0; r < 4; ++r) Xch[w][mt * 16 + cr + r][nt * 16 + cc] = acc[mt][nt][r];
  __syncthreads();
  const int row = tid >> 3, col0 = (tid & 7) << 2;
  const int b = rb + row;
  const __hip_bfloat16* xp = XP + (size_t)b * G4;
#pragma unroll
  for (int j = 0; j < 4; ++j) {
    const int col = col0 + j, gc = gc0 + col;
    float xi = __bfloat162float(xp[gc]) + Xch[0][row][col];
    float xf = __bfloat162float(xp[HP + gc]) + Xch[1][row][col];
    float xg = __bfloat162float(xp[2 * HP + gc]) + Xch[2][row][col];
    float xo = __bfloat162float(xp[3 * HP + gc]) + Xch[3][row][col];
    if (gc < 1150) {
      const int ci = b * HP + gc;
      float cold = Cst[ci];
      float si = 1.f / (1.f + expf(-xi));
      float sf = 1.f / (1.f + expf(-xf));
      float so = 1.f / (1.f + expf(-xo));
      float cn = sf * cold + si * tanhf(xg);
      float hn = so * tanhf(cn);
      Cst[ci] = cn;
      Hout[ci] = __float2bfloat16(hn);
      if (Yout) Yout[(size_t)b * 1150 + gc] = hn;
      if (HT) {
        HT[b * 1150 + gc] = hn;
        CT[b * 1150 + gc] = cn;
      }
    } else {
      Hout[b * HP + gc] = __float2bfloat16(0.f);  // keep K-pad cols zero for next GEMM
    }
  }
}

// ---------------- launch ----------------

extern "C" void kernel_launch(void* const* d_in, const int* in_sizes, int n_in,
                              void* d_out, int out_size, void* d_ws, size_t ws_size,
                              hipStream_t stream) {
  const int* tok = (const int*)d_in[0];
  const float* h0 = (const float*)d_in[1];
  const float* c0 = (const float*)d_in[2];
  const float* emb = (const float*)d_in[3];
  const float *Wih[3], *Whh[3], *bih[3], *bhh[3];
  for (int l = 0; l < 3; ++l) {
    Wih[l] = (const float*)d_in[4 + 4 * l];
    Whh[l] = (const float*)d_in[5 + 4 * l];
    bih[l] = (const float*)d_in[6 + 4 * l];
    bhh[l] = (const float*)d_in[7 + 4 * l];
  }
  float* out = (float*)d_out;

  char* ws = (char*)d_ws;
  size_t off = 0;
  auto alloc = [&](size_t bytes) -> char* {
    char* p = ws + off;
    off += (bytes + 255) & ~(size_t)255;
    return p;
  };
  __hip_bfloat16* x0 = (__hip_bfloat16*)alloc((size_t)MT * KP0 * 2);
  __hip_bfloat16* ys = (__hip_bfloat16*)alloc((size_t)(MT + 128) * HP * 2);  // block0 = h_init
  __hip_bfloat16* xproj = (__hip_bfloat16*)alloc((size_t)CH * 128 * G4 * 2); // 50-step chunk
  __hip_bfloat16 *Wihp[3], *Whhp[3];
  float* biasp[3];
  Wihp[0] = (__hip_bfloat16*)alloc((size_t)G4 * KP0 * 2);
  Wihp[1] = (__hip_bfloat16*)alloc((size_t)G4 * HP * 2);
  Wihp[2] = (__hip_bfloat16*)alloc((size_t)G4 * HP * 2);
  for (int l = 0; l < 3; ++l) Whhp[l] = (__hip_bfloat16*)alloc((size_t)G4 * HP * 2);
  for (int l = 0; l < 3; ++l) biasp[l] = (float*)alloc((size_t)G4 * 4);
  float* cst = (float*)alloc((size_t)128 * HP * 4);

  for (int l = 0; l < 3; ++l) {
    k_packw<<<2048, 256, 0, stream>>>(Wih[l], Wihp[l], l == 0 ? 400 : 1150, l == 0 ? KP0 : HP);
    k_packw<<<2048, 256, 0, stream>>>(Whh[l], Whhp[l], 1150, HP);
    k_packb<<<18, 256, 0, stream>>>(bih[l], bhh[l], biasp[l]);
  }
  k_embed<<<2048, 256, 0, stream>>>(tok, emb, x0);

  const __hip_bfloat16* Xin = x0;
  int Kp = KP0;
  for (int l = 0; l < 3; ++l) {
    k_inith<<<576, 256, 0, stream>>>(h0 + (size_t)l * 128 * 1150, ys);
    k_initc<<<576, 256, 0, stream>>>(c0 + (size_t)l * 128 * 1150, cst);
    for (int t0 = 0; t0 < 200; t0 += CH) {
      // input projection for timesteps [t0, t0+CH): 50*128 rows, grid 50*36=1800
      k_gemm<<<CH * 36, 256, 0, stream>>>(Xin + (size_t)t0 * 128 * Kp, Wihp[l],
                                          biasp[l], xproj, Kp);
      for (int t = t0; t < t0 + CH; ++t) {
        float* Yp = (l == 2) ? out + (size_t)t * 128 * 1150 : nullptr;
        float* HTp = (t == 199) ? out + 29440000 + (size_t)l * 147200 : nullptr;
        float* CTp = (t == 199) ? out + 29881600 + (size_t)l * 147200 : nullptr;
        k_step<<<144, 256, 0, stream>>>(ys + (size_t)t * 128 * HP, Whhp[l],
                                        xproj + (size_t)(t - t0) * 128 * G4, cst,
                                        ys + (size_t)(t + 1) * 128 * HP, Yp, HTp, CTp);
      }
    }
    Xin = ys + (size_t)128 * HP;  // layer output rows 128.. are next layer's input
    Kp = HP;
  }
}